// Round 2
// baseline (402.821 us; speedup 1.0000x reference)
//
#include <hip/hip_runtime.h>
#include <hip/hip_bf16.h>

// BATCH=131072, FEAT=512, NUM_CLASS=8192.
// Pipeline: memset(counts) -> hist -> scan(writes fill=excl prefix) ->
// scatter(rows bucketed by class, fill advances to end) ->
// per-class gather-sum (start = fill[c]-counts[c]), unroll-8 for MLP.

#define FEAT 512
#define FEAT4 128           // FEAT/4 float4s per row
#define SCAN_THREADS 256

__global__ void k_hist(const int* __restrict__ targets, int* __restrict__ counts, int batch) {
    int i = blockIdx.x * blockDim.x + threadIdx.x;
    if (i < batch) atomicAdd(&counts[targets[i]], 1);
}

// Exclusive scan of num_class bins, one block of 256 threads.
// Coalesced global<->LDS staging; +i/32 padding kills the stride-32 bank conflict.
__global__ __launch_bounds__(SCAN_THREADS) void k_scan(const int* __restrict__ counts,
                                                       int* __restrict__ fill,
                                                       int num_class) {
    __shared__ int sh[8192 + 256];          // padded: idx i -> i + (i>>5)
    __shared__ int sums[SCAN_THREADS];
    const int t = threadIdx.x;
    const int bins = num_class / SCAN_THREADS;   // 32

    for (int i = t; i < num_class; i += SCAN_THREADS) sh[i + (i >> 5)] = counts[i];
    __syncthreads();

    const int base = t * bins;
    int s = 0;
    for (int i = 0; i < bins; ++i) { int idx = base + i; s += sh[idx + (idx >> 5)]; }
    sums[t] = s;
    __syncthreads();
    for (int off = 1; off < SCAN_THREADS; off <<= 1) {
        int v = (t >= off) ? sums[t - off] : 0;
        __syncthreads();
        sums[t] += v;
        __syncthreads();
    }
    int run = sums[t] - s;                  // exclusive prefix of this thread's range
    for (int i = 0; i < bins; ++i) {
        int idx = base + i;
        int c = sh[idx + (idx >> 5)];
        sh[idx + (idx >> 5)] = run;
        run += c;
    }
    __syncthreads();
    for (int i = t; i < num_class; i += SCAN_THREADS) fill[i] = sh[i + (i >> 5)];
}

__global__ void k_scatter(const int* __restrict__ targets, int* __restrict__ fill,
                          int* __restrict__ rows, int batch) {
    int i = blockIdx.x * blockDim.x + threadIdx.x;
    if (i < batch) {
        int pos = atomicAdd(&fill[targets[i]], 1);
        rows[pos] = i;
    }
}

// One block (128 threads) per class. Each thread owns one float4 column.
// Unroll-by-8: 8 independent dwordx4 loads in flight per wave.
__global__ __launch_bounds__(128) void k_sum(const float4* __restrict__ batch,
                                             const float4* __restrict__ csums,
                                             const int* __restrict__ fill,
                                             const int* __restrict__ counts,
                                             const int* __restrict__ rows,
                                             float4* __restrict__ out) {
    const int c = blockIdx.x;
    const int t = threadIdx.x;      // 0..127
    const int n = counts[c];
    const int start = fill[c] - n;  // fill advanced to end during scatter

    float4 acc = csums[(size_t)c * FEAT4 + t];

    __shared__ int sidx[512];
    for (int chunk = 0; chunk < n; chunk += 512) {
        const int m = min(n - chunk, 512);
        for (int j = t; j < m; j += 128) sidx[j] = rows[start + chunk + j];
        __syncthreads();

        int j = 0;
        for (; j + 8 <= m; j += 8) {
            float4 v0 = batch[(size_t)sidx[j + 0] * FEAT4 + t];
            float4 v1 = batch[(size_t)sidx[j + 1] * FEAT4 + t];
            float4 v2 = batch[(size_t)sidx[j + 2] * FEAT4 + t];
            float4 v3 = batch[(size_t)sidx[j + 3] * FEAT4 + t];
            float4 v4 = batch[(size_t)sidx[j + 4] * FEAT4 + t];
            float4 v5 = batch[(size_t)sidx[j + 5] * FEAT4 + t];
            float4 v6 = batch[(size_t)sidx[j + 6] * FEAT4 + t];
            float4 v7 = batch[(size_t)sidx[j + 7] * FEAT4 + t];
            acc.x += ((v0.x + v1.x) + (v2.x + v3.x)) + ((v4.x + v5.x) + (v6.x + v7.x));
            acc.y += ((v0.y + v1.y) + (v2.y + v3.y)) + ((v4.y + v5.y) + (v6.y + v7.y));
            acc.z += ((v0.z + v1.z) + (v2.z + v3.z)) + ((v4.z + v5.z) + (v6.z + v7.z));
            acc.w += ((v0.w + v1.w) + (v2.w + v3.w)) + ((v4.w + v5.w) + (v6.w + v7.w));
        }
        for (; j < m; ++j) {
            float4 v = batch[(size_t)sidx[j] * FEAT4 + t];
            acc.x += v.x; acc.y += v.y; acc.z += v.z; acc.w += v.w;
        }
        __syncthreads();
    }
    out[(size_t)c * FEAT4 + t] = acc;
}

// ---------- fallback: plain atomic scatter-add (if ws too small) ----------
__global__ void k_copy(const float4* __restrict__ src, float4* __restrict__ dst, int n4) {
    int i = blockIdx.x * blockDim.x + threadIdx.x;
    if (i < n4) dst[i] = src[i];
}

__global__ __launch_bounds__(128) void k_atomic(const float4* __restrict__ batch,
                                                const int* __restrict__ targets,
                                                float* __restrict__ out, int batch_n) {
    const int r = blockIdx.x;
    const int t = threadIdx.x;
    if (r >= batch_n) return;
    float4 v = batch[(size_t)r * FEAT4 + t];
    float* o = out + (size_t)targets[r] * FEAT + t * 4;
    atomicAdd(o + 0, v.x);
    atomicAdd(o + 1, v.y);
    atomicAdd(o + 2, v.z);
    atomicAdd(o + 3, v.w);
}

extern "C" void kernel_launch(void* const* d_in, const int* in_sizes, int n_in,
                              void* d_out, int out_size, void* d_ws, size_t ws_size,
                              hipStream_t stream) {
    const float* batch_samples = (const float*)d_in[0];
    const float* class_sums    = (const float*)d_in[1];
    const int*   targets       = (const int*)d_in[2];
    // d_in[3] (idx) unused in forward math.

    const int batch     = in_sizes[2];          // 131072
    const int num_class = out_size / FEAT;      // 8192
    float* out = (float*)d_out;

    const size_t need = (size_t)num_class * 4 * 2 + (size_t)batch * 4;
    if (ws_size >= need && (num_class % SCAN_THREADS) == 0 && num_class <= 8192) {
        int* counts = (int*)d_ws;
        int* fill   = counts + num_class;
        int* rows   = fill + num_class;

        hipMemsetAsync(counts, 0, (size_t)num_class * 4, stream);
        k_hist<<<(batch + 255) / 256, 256, 0, stream>>>(targets, counts, batch);
        k_scan<<<1, SCAN_THREADS, 0, stream>>>(counts, fill, num_class);
        k_scatter<<<(batch + 255) / 256, 256, 0, stream>>>(targets, fill, rows, batch);
        k_sum<<<num_class, 128, 0, stream>>>((const float4*)batch_samples,
                                             (const float4*)class_sums,
                                             fill, counts, rows,
                                             (float4*)out);
    } else {
        const int n4 = out_size / 4;
        k_copy<<<(n4 + 255) / 256, 256, 0, stream>>>((const float4*)class_sums,
                                                     (float4*)out, n4);
        k_atomic<<<batch, 128, 0, stream>>>((const float4*)batch_samples,
                                            targets, out, batch);
    }
}

// Round 4
// 379.741 us; speedup vs baseline: 1.0608x; 1.0608x over previous
//
#include <hip/hip_runtime.h>
#include <hip/hip_bf16.h>

// BATCH=131072, FEAT=512, NUM_CLASS=8192.
// Pipeline: memset(counts) -> hist(int4) -> scan -> scatter(int4, buckets rows
// by class) -> per-class gather-sum (nontemporal float4 streaming).

#define FEAT 512
#define FEAT4 128           // FEAT/4 float4s per row
#define SCAN_THREADS 256

typedef float f4 __attribute__((ext_vector_type(4)));   // clang-native vec4

__global__ void k_hist(const int4* __restrict__ t4, int* __restrict__ counts,
                       int n4, const int* __restrict__ targets, int batch) {
    int i = blockIdx.x * blockDim.x + threadIdx.x;
    if (i < n4) {
        int4 v = t4[i];
        atomicAdd(&counts[v.x], 1);
        atomicAdd(&counts[v.y], 1);
        atomicAdd(&counts[v.z], 1);
        atomicAdd(&counts[v.w], 1);
    }
    if (i == 0) {                       // tail (batch not multiple of 4)
        for (int k = n4 * 4; k < batch; ++k) atomicAdd(&counts[targets[k]], 1);
    }
}

// Exclusive scan of num_class bins, one block of 256 threads.
__global__ __launch_bounds__(SCAN_THREADS) void k_scan(const int* __restrict__ counts,
                                                       int* __restrict__ fill,
                                                       int num_class) {
    __shared__ int sh[8192 + 256];          // padded: idx i -> i + (i>>5)
    __shared__ int sums[SCAN_THREADS];
    const int t = threadIdx.x;
    const int bins = num_class / SCAN_THREADS;   // 32

    for (int i = t; i < num_class; i += SCAN_THREADS) sh[i + (i >> 5)] = counts[i];
    __syncthreads();

    const int base = t * bins;
    int s = 0;
    for (int i = 0; i < bins; ++i) { int idx = base + i; s += sh[idx + (idx >> 5)]; }
    sums[t] = s;
    __syncthreads();
    for (int off = 1; off < SCAN_THREADS; off <<= 1) {
        int v = (t >= off) ? sums[t - off] : 0;
        __syncthreads();
        sums[t] += v;
        __syncthreads();
    }
    int run = sums[t] - s;
    for (int i = 0; i < bins; ++i) {
        int idx = base + i;
        int c = sh[idx + (idx >> 5)];
        sh[idx + (idx >> 5)] = run;
        run += c;
    }
    __syncthreads();
    for (int i = t; i < num_class; i += SCAN_THREADS) fill[i] = sh[i + (i >> 5)];
}

__global__ void k_scatter(const int4* __restrict__ t4, int* __restrict__ fill,
                          int* __restrict__ rows, int n4,
                          const int* __restrict__ targets, int batch) {
    int i = blockIdx.x * blockDim.x + threadIdx.x;
    if (i < n4) {
        int4 v = t4[i];
        int r = i * 4;
        rows[atomicAdd(&fill[v.x], 1)] = r + 0;
        rows[atomicAdd(&fill[v.y], 1)] = r + 1;
        rows[atomicAdd(&fill[v.z], 1)] = r + 2;
        rows[atomicAdd(&fill[v.w], 1)] = r + 3;
    }
    if (i == 0) {
        for (int k = n4 * 4; k < batch; ++k)
            rows[atomicAdd(&fill[targets[k]], 1)] = k;
    }
}

// One block (128 threads) per class. Each thread owns one float4 column.
// Nontemporal streaming loads (batch rows are read exactly once).
__global__ __launch_bounds__(128) void k_sum(const f4* __restrict__ batch,
                                             const f4* __restrict__ csums,
                                             const int* __restrict__ fill,
                                             const int* __restrict__ counts,
                                             const int* __restrict__ rows,
                                             f4* __restrict__ out) {
    const int c = blockIdx.x;
    const int t = threadIdx.x;      // 0..127
    const int n = counts[c];
    const int start = fill[c] - n;  // fill advanced to end during scatter

    f4 acc = csums[(size_t)c * FEAT4 + t];

    __shared__ int sidx[512];
    for (int chunk = 0; chunk < n; chunk += 512) {
        const int m = min(n - chunk, 512);
        for (int j = t; j < m; j += 128) sidx[j] = rows[start + chunk + j];
        __syncthreads();

        int j = 0;
        for (; j + 8 <= m; j += 8) {
            f4 v0 = __builtin_nontemporal_load(&batch[(size_t)sidx[j + 0] * FEAT4 + t]);
            f4 v1 = __builtin_nontemporal_load(&batch[(size_t)sidx[j + 1] * FEAT4 + t]);
            f4 v2 = __builtin_nontemporal_load(&batch[(size_t)sidx[j + 2] * FEAT4 + t]);
            f4 v3 = __builtin_nontemporal_load(&batch[(size_t)sidx[j + 3] * FEAT4 + t]);
            f4 v4 = __builtin_nontemporal_load(&batch[(size_t)sidx[j + 4] * FEAT4 + t]);
            f4 v5 = __builtin_nontemporal_load(&batch[(size_t)sidx[j + 5] * FEAT4 + t]);
            f4 v6 = __builtin_nontemporal_load(&batch[(size_t)sidx[j + 6] * FEAT4 + t]);
            f4 v7 = __builtin_nontemporal_load(&batch[(size_t)sidx[j + 7] * FEAT4 + t]);
            acc += ((v0 + v1) + (v2 + v3)) + ((v4 + v5) + (v6 + v7));
        }
        for (; j < m; ++j) {
            f4 v = __builtin_nontemporal_load(&batch[(size_t)sidx[j] * FEAT4 + t]);
            acc += v;
        }
        __syncthreads();
    }
    __builtin_nontemporal_store(acc, &out[(size_t)c * FEAT4 + t]);
}

// ---------- fallback: plain atomic scatter-add (if ws too small) ----------
__global__ void k_copy(const float4* __restrict__ src, float4* __restrict__ dst, int n4) {
    int i = blockIdx.x * blockDim.x + threadIdx.x;
    if (i < n4) dst[i] = src[i];
}

__global__ __launch_bounds__(128) void k_atomic(const float4* __restrict__ batch,
                                                const int* __restrict__ targets,
                                                float* __restrict__ out, int batch_n) {
    const int r = blockIdx.x;
    const int t = threadIdx.x;
    if (r >= batch_n) return;
    float4 v = batch[(size_t)r * FEAT4 + t];
    float* o = out + (size_t)targets[r] * FEAT + t * 4;
    atomicAdd(o + 0, v.x);
    atomicAdd(o + 1, v.y);
    atomicAdd(o + 2, v.z);
    atomicAdd(o + 3, v.w);
}

extern "C" void kernel_launch(void* const* d_in, const int* in_sizes, int n_in,
                              void* d_out, int out_size, void* d_ws, size_t ws_size,
                              hipStream_t stream) {
    const float* batch_samples = (const float*)d_in[0];
    const float* class_sums    = (const float*)d_in[1];
    const int*   targets       = (const int*)d_in[2];
    // d_in[3] (idx) unused in forward math.

    const int batch     = in_sizes[2];          // 131072
    const int num_class = out_size / FEAT;      // 8192
    float* out = (float*)d_out;

    const size_t need = (size_t)num_class * 4 * 2 + (size_t)batch * 4;
    if (ws_size >= need && (num_class % SCAN_THREADS) == 0 && num_class <= 8192) {
        int* counts = (int*)d_ws;
        int* fill   = counts + num_class;
        int* rows   = fill + num_class;
        const int n4 = batch / 4;

        (void)hipMemsetAsync(counts, 0, (size_t)num_class * 4, stream);
        k_hist<<<(n4 + 255) / 256, 256, 0, stream>>>((const int4*)targets, counts,
                                                     n4, targets, batch);
        k_scan<<<1, SCAN_THREADS, 0, stream>>>(counts, fill, num_class);
        k_scatter<<<(n4 + 255) / 256, 256, 0, stream>>>((const int4*)targets, fill,
                                                        rows, n4, targets, batch);
        k_sum<<<num_class, 128, 0, stream>>>((const f4*)batch_samples,
                                             (const f4*)class_sums,
                                             fill, counts, rows,
                                             (f4*)out);
    } else {
        const int nv4 = out_size / 4;
        k_copy<<<(nv4 + 255) / 256, 256, 0, stream>>>((const float4*)class_sums,
                                                      (float4*)out, nv4);
        k_atomic<<<batch, 128, 0, stream>>>((const float4*)batch_samples,
                                            targets, out, batch);
    }
}

// Round 5
// 374.684 us; speedup vs baseline: 1.0751x; 1.0135x over previous
//
#include <hip/hip_runtime.h>
#include <hip/hip_bf16.h>

// BATCH=131072, FEAT=512, NUM_CLASS=8192.
// Pipeline: memset(fill+ovf_cnt) -> bucket-scatter (rows_buf[c*CAP+pos]) ->
// per-class gather-sum (nontemporal float4) -> overflow fixup (atomics; empty
// in practice, present for unconditional correctness).

#define FEAT 512
#define FEAT4 128           // FEAT/4 float4s per row
#define CAP   128           // bucket capacity per class (Poisson(16) -> never hit)

typedef float f4 __attribute__((ext_vector_type(4)));   // clang-native vec4

__device__ __forceinline__ void bucket_one(int c, int row, int* __restrict__ fill,
                                           int* __restrict__ rows_buf,
                                           int* __restrict__ ovf_cnt,
                                           int* __restrict__ ovf) {
    int pos = atomicAdd(&fill[c], 1);
    if (pos < CAP) rows_buf[c * CAP + pos] = row;
    else           ovf[atomicAdd(ovf_cnt, 1)] = row;
}

__global__ void k_scatter(const int4* __restrict__ t4, int* __restrict__ fill,
                          int* __restrict__ rows_buf, int* __restrict__ ovf_cnt,
                          int* __restrict__ ovf, int n4,
                          const int* __restrict__ targets, int batch) {
    int i = blockIdx.x * blockDim.x + threadIdx.x;
    if (i < n4) {
        int4 v = t4[i];
        int r = i * 4;
        bucket_one(v.x, r + 0, fill, rows_buf, ovf_cnt, ovf);
        bucket_one(v.y, r + 1, fill, rows_buf, ovf_cnt, ovf);
        bucket_one(v.z, r + 2, fill, rows_buf, ovf_cnt, ovf);
        bucket_one(v.w, r + 3, fill, rows_buf, ovf_cnt, ovf);
    }
    if (i == 0) {                        // tail (batch not multiple of 4)
        for (int k = n4 * 4; k < batch; ++k)
            bucket_one(targets[k], k, fill, rows_buf, ovf_cnt, ovf);
    }
}

// One block (128 threads) per class; each thread owns one float4 column.
// n <= CAP rows handled here; the rest (if any) via k_ovf.
__global__ __launch_bounds__(128) void k_sum(const f4* __restrict__ batch,
                                             const f4* __restrict__ csums,
                                             const int* __restrict__ fill,
                                             const int* __restrict__ rows_buf,
                                             f4* __restrict__ out) {
    const int c = blockIdx.x;
    const int t = threadIdx.x;      // 0..127
    const int n = min(fill[c], CAP);

    __shared__ int sidx[CAP];
    if (t < n) sidx[t] = rows_buf[c * CAP + t];
    __syncthreads();

    f4 acc = csums[(size_t)c * FEAT4 + t];

    int j = 0;
    for (; j + 8 <= n; j += 8) {
        f4 v0 = __builtin_nontemporal_load(&batch[(size_t)sidx[j + 0] * FEAT4 + t]);
        f4 v1 = __builtin_nontemporal_load(&batch[(size_t)sidx[j + 1] * FEAT4 + t]);
        f4 v2 = __builtin_nontemporal_load(&batch[(size_t)sidx[j + 2] * FEAT4 + t]);
        f4 v3 = __builtin_nontemporal_load(&batch[(size_t)sidx[j + 3] * FEAT4 + t]);
        f4 v4 = __builtin_nontemporal_load(&batch[(size_t)sidx[j + 4] * FEAT4 + t]);
        f4 v5 = __builtin_nontemporal_load(&batch[(size_t)sidx[j + 5] * FEAT4 + t]);
        f4 v6 = __builtin_nontemporal_load(&batch[(size_t)sidx[j + 6] * FEAT4 + t]);
        f4 v7 = __builtin_nontemporal_load(&batch[(size_t)sidx[j + 7] * FEAT4 + t]);
        acc += ((v0 + v1) + (v2 + v3)) + ((v4 + v5) + (v6 + v7));
    }
    for (; j < n; ++j)
        acc += __builtin_nontemporal_load(&batch[(size_t)sidx[j] * FEAT4 + t]);

    __builtin_nontemporal_store(acc, &out[(size_t)c * FEAT4 + t]);
}

// Overflow fixup: float atomics into out. Runs after k_sum; cnt==0 in practice.
__global__ __launch_bounds__(128) void k_ovf(const f4* __restrict__ batch,
                                             const int* __restrict__ targets,
                                             const int* __restrict__ ovf_cnt,
                                             const int* __restrict__ ovf,
                                             float* __restrict__ out) {
    const int cnt = *ovf_cnt;
    const int t = threadIdx.x;
    for (int e = blockIdx.x; e < cnt; e += gridDim.x) {
        int row = ovf[e];
        int c = targets[row];
        f4 v = batch[(size_t)row * FEAT4 + t];
        float* o = out + (size_t)c * FEAT + t * 4;
        atomicAdd(o + 0, v.x);
        atomicAdd(o + 1, v.y);
        atomicAdd(o + 2, v.z);
        atomicAdd(o + 3, v.w);
    }
}

// ---------- fallback: plain atomic scatter-add (if ws too small) ----------
__global__ void k_copy(const float4* __restrict__ src, float4* __restrict__ dst, int n4) {
    int i = blockIdx.x * blockDim.x + threadIdx.x;
    if (i < n4) dst[i] = src[i];
}

__global__ __launch_bounds__(128) void k_atomic(const float4* __restrict__ batch,
                                                const int* __restrict__ targets,
                                                float* __restrict__ out, int batch_n) {
    const int r = blockIdx.x;
    const int t = threadIdx.x;
    if (r >= batch_n) return;
    float4 v = batch[(size_t)r * FEAT4 + t];
    float* o = out + (size_t)targets[r] * FEAT + t * 4;
    atomicAdd(o + 0, v.x);
    atomicAdd(o + 1, v.y);
    atomicAdd(o + 2, v.z);
    atomicAdd(o + 3, v.w);
}

extern "C" void kernel_launch(void* const* d_in, const int* in_sizes, int n_in,
                              void* d_out, int out_size, void* d_ws, size_t ws_size,
                              hipStream_t stream) {
    const float* batch_samples = (const float*)d_in[0];
    const float* class_sums    = (const float*)d_in[1];
    const int*   targets       = (const int*)d_in[2];
    // d_in[3] (idx) unused in forward math.

    const int batch     = in_sizes[2];          // 131072
    const int num_class = out_size / FEAT;      // 8192
    float* out = (float*)d_out;

    // ws layout (ints): fill[num_class] | ovf_cnt[1] | pad | rows_buf[num_class*CAP] | ovf[batch]
    const size_t rows_off = ((size_t)num_class + 64) & ~63ull;   // 256B-align
    const size_t ovf_off  = rows_off + (size_t)num_class * CAP;
    const size_t need     = (ovf_off + (size_t)batch) * 4;

    if (ws_size >= need) {
        int* fill     = (int*)d_ws;
        int* ovf_cnt  = fill + num_class;
        int* rows_buf = fill + rows_off;
        int* ovf      = fill + ovf_off;
        const int n4 = batch / 4;

        (void)hipMemsetAsync(fill, 0, ((size_t)num_class + 1) * 4, stream);
        k_scatter<<<(n4 + 255) / 256, 256, 0, stream>>>((const int4*)targets, fill,
                                                        rows_buf, ovf_cnt, ovf,
                                                        n4, targets, batch);
        k_sum<<<num_class, 128, 0, stream>>>((const f4*)batch_samples,
                                             (const f4*)class_sums,
                                             fill, rows_buf, (f4*)out);
        k_ovf<<<256, 128, 0, stream>>>((const f4*)batch_samples, targets,
                                       ovf_cnt, ovf, out);
    } else {
        const int nv4 = out_size / 4;
        k_copy<<<(nv4 + 255) / 256, 256, 0, stream>>>((const float4*)class_sums,
                                                      (float4*)out, nv4);
        k_atomic<<<batch, 128, 0, stream>>>((const float4*)batch_samples,
                                            targets, out, batch);
    }
}